// Round 4
// baseline (371.294 us; speedup 1.0000x reference)
//
#include <hip/hip_runtime.h>
#include <math.h>

#define NN 500
#define TT 48
#define NT 24000   // NN*TT
#define NF4 6000   // NT/4

// ---------- kernel 0a: row sums of s ----------
__global__ void k_srow(const float* __restrict__ s, float* __restrict__ srow) {
    int r = blockIdx.x;
    int l = threadIdx.x;
    float v = 0.f;
    for (int j = l; j < NN; j += 64) v += s[r * NN + j];
    #pragma unroll
    for (int o = 32; o; o >>= 1) v += __shfl_xor(v, o);
    if (l == 0) srow[r] = v;
}

// ---------- kernel 0b: rowsum[k] = (47 - k/500)*0.8 + srow[k%500] ----------
__global__ void k_rs(const float* __restrict__ srow, float* __restrict__ rs) {
    int k = blockIdx.x * 256 + threadIdx.x;
    if (k < NT) {
        int i = k / NN;
        int v = k - i * NN;
        rs[k] = (float)(TT - 1 - i) * 0.8f + srow[v];
    }
}

// ---------- kernel 1: per-(b,c) softmax over 24000 folded to per-n sums ----------
// (unchanged from round 3 — this round is a timing ablation probe)
__launch_bounds__(512, 4)
__global__ void k_p1(const float* __restrict__ x, const float* __restrict__ rs,
                     float* __restrict__ xws) {
    __shared__ float p[6144];          // per-float4 contributions (f-indexed)
    __shared__ float redm[8], reds[8];
    int bc = blockIdx.x;
    int tid = threadIdx.x;
    int w = tid >> 6, l = tid & 63;
    int f0 = w * 768 + l;

    const float4* xp = (const float4*)x + (size_t)bc * NF4;
    const float4* rp = (const float4*)rs;

    float sf[12], ml[12];
    float m = 0.f;                     // relu output >= 0, so 0 is a safe identity
    #pragma unroll
    for (int i = 0; i < 12; i++) {
        int f = f0 + i * 64;
        int fc = (f < NF4) ? f : (NF4 - 1);     // clamped: load unconditionally
        float msk = (f < NF4) ? 1.f : 0.f;
        float4 xv = xp[fc];
        float4 rv = rp[fc];
        float y0 = fmaxf(xv.x * rv.x * 0.125f, 0.f);
        float y1 = fmaxf(xv.y * rv.y * 0.125f, 0.f);
        float y2 = fmaxf(xv.z * rv.z * 0.125f, 0.f);
        float y3 = fmaxf(xv.w * rv.w * 0.125f, 0.f);
        float mm = fmaxf(fmaxf(y0, y1), fmaxf(y2, y3));
        float sfi = __expf(y0 - mm) + __expf(y1 - mm)
                  + __expf(y2 - mm) + __expf(y3 - mm);
        ml[i] = mm * msk;
        sf[i] = sfi * msk;
        m = fmaxf(m, ml[i]);
    }

    // block max over 8 waves
    #pragma unroll
    for (int o = 32; o; o >>= 1) m = fmaxf(m, __shfl_xor(m, o));
    if (l == 0) redm[w] = m;
    __syncthreads();
    float M = redm[0];
    #pragma unroll
    for (int i = 1; i < 8; i++) M = fmaxf(M, redm[i]);

    // rescale per-float4 sums -> LDS (conflict-free writes), lane total -> Z
    float tot = 0.f;
    #pragma unroll
    for (int i = 0; i < 12; i++) {
        float cf = sf[i] * __expf(ml[i] - M);
        p[f0 + i * 64] = cf;
        tot += cf;
    }
    #pragma unroll
    for (int o = 32; o; o >>= 1) tot += __shfl_xor(tot, o);
    if (l == 0) reds[w] = tot;
    __syncthreads();
    float Z = 0.f;
    #pragma unroll
    for (int i = 0; i < 8; i++) Z += reds[i];

    // thread n gathers node n's 12 consecutive partials
    if (tid < NN) {
        const float* pp = p + tid * 12;
        float sn = 0.f;
        #pragma unroll
        for (int j = 0; j < 12; j++) sn += pp[j];
        xws[(size_t)bc * NN + tid] = sn / Z;
    }
}

// ---------- kernel 2: gram (X^T X over C=64) fused with row softmax ----------
// (unchanged from round 3 — this round is a timing ablation probe)
__launch_bounds__(512, 4)
__global__ void k_p2(const float* __restrict__ xws, float* __restrict__ out) {
    __shared__ __align__(16) float Xs[32 * NN + 16];
    int b = blockIdx.y;
    int rt8 = blockIdx.x;   // 0..7
    int tid = threadIdx.x;

    int rt = tid >> 6, cx = tid & 63;
    int r0 = rt8 * 64 + rt * 8;
    int cb0 = cx * 4, cb1 = cx * 4 + 256;

    float acc[8][8];
    #pragma unroll
    for (int i = 0; i < 8; i++)
        #pragma unroll
        for (int j = 0; j < 8; j++) acc[i][j] = 0.f;

    for (int cbk = 0; cbk < 2; cbk++) {
        // stage channels [32*cbk, 32*cbk+32) of X_b: 4000 float4
        const float4* src4 = (const float4*)(xws + ((size_t)b * 64 + 32 * cbk) * NN);
        __syncthreads();                 // protect previous Xs use
        #pragma unroll
        for (int i = 0; i < 8; i++) {
            int idx = tid + i * 512;
            if (idx < 4000) ((float4*)Xs)[idx] = src4[idx];
        }
        if (tid < 16) Xs[32 * NN + tid] = 0.f;   // zero the guard pad
        __syncthreads();

        #pragma unroll 4
        for (int c = 0; c < 32; c++) {
            const float* row = Xs + c * NN;
            float4 a0 = *(const float4*)(row + r0);       // broadcast (uniform addr)
            float4 a1 = *(const float4*)(row + r0 + 4);
            float4 b0 = *(const float4*)(row + cb0);      // lanes contiguous 16B
            float4 b1 = *(const float4*)(row + cb1);
            float av[8] = {a0.x, a0.y, a0.z, a0.w, a1.x, a1.y, a1.z, a1.w};
            float bv[8] = {b0.x, b0.y, b0.z, b0.w, b1.x, b1.y, b1.z, b1.w};
            #pragma unroll
            for (int i = 0; i < 8; i++)
                #pragma unroll
                for (int j = 0; j < 8; j++)
                    acc[i][j] = fmaf(av[i], bv[j], acc[i][j]);
        }
    }

    bool c1v = (cx <= 60);          // chunk1 cols 256+4cx valid iff cx<=60
    size_t ob = (size_t)b * (NN * NN);
    #pragma unroll 1
    for (int ri = 0; ri < 8; ri++) {
        int r = r0 + ri;
        if (r >= NN) break;         // wave-uniform
        float u[8];
        #pragma unroll
        for (int j = 0; j < 8; j++) u[j] = fmaxf(acc[ri][j], 0.f) * 0.125f;
        float mx = fmaxf(fmaxf(u[0], u[1]), fmaxf(u[2], u[3]));
        if (c1v) mx = fmaxf(mx, fmaxf(fmaxf(u[4], u[5]), fmaxf(u[6], u[7])));
        #pragma unroll
        for (int o = 32; o; o >>= 1) mx = fmaxf(mx, __shfl_xor(mx, o));

        float e[8];
        float es = 0.f;
        #pragma unroll
        for (int j = 0; j < 4; j++) { e[j] = __expf(u[j] - mx); es += e[j]; }
        if (c1v) {
            #pragma unroll
            for (int j = 4; j < 8; j++) { e[j] = __expf(u[j] - mx); es += e[j]; }
        }
        #pragma unroll
        for (int o = 32; o; o >>= 1) es += __shfl_xor(es, o);
        float inv = 1.f / es;

        float4 w0 = make_float4(e[0] * inv, e[1] * inv, e[2] * inv, e[3] * inv);
        *(float4*)(out + ob + (size_t)r * NN + cb0) = w0;
        if (c1v) {
            float4 w1 = make_float4(e[4] * inv, e[5] * inv, e[6] * inv, e[7] * inv);
            *(float4*)(out + ob + (size_t)r * NN + cb1) = w1;
        }
    }
}

extern "C" void kernel_launch(void* const* d_in, const int* in_sizes, int n_in,
                              void* d_out, int out_size, void* d_ws, size_t ws_size,
                              hipStream_t stream) {
    const float* x = (const float*)d_in[0];   // [64,64,500,48]
    const float* s = (const float*)d_in[1];   // [500,500]
    float* out = (float*)d_out;               // [64,500,500]
    float* wsf = (float*)d_ws;

    float* srow = wsf;             // 500 floats
    float* rs   = wsf + 1024;      // 24000 floats
    float* xws  = wsf + 32768;     // 64*64*500 = 2,048,000 floats (~8.2 MB)

    k_srow<<<NN, 64, 0, stream>>>(s, srow);
    k_rs<<<(NT + 255) / 256, 256, 0, stream>>>(srow, rs);

    // ---- ABLATION PROBE: p1 launched 2x, p2 launched 3x (both idempotent).
    // dur_probe - 169.5 = t_p1 + 2*t_p2  -> solves the per-kernel split.
    k_p1<<<64 * 64, 512, 0, stream>>>(x, rs, xws);
    k_p1<<<64 * 64, 512, 0, stream>>>(x, rs, xws);
    dim3 g2(8, 64);
    k_p2<<<g2, 512, 0, stream>>>(xws, out);
    k_p2<<<g2, 512, 0, stream>>>(xws, out);
    k_p2<<<g2, 512, 0, stream>>>(xws, out);
}

// Round 6
// 177.421 us; speedup vs baseline: 2.0927x; 2.0927x over previous
//
#include <hip/hip_runtime.h>
#include <math.h>

#define NN 500
#define TT 48
#define NT 24000   // NN*TT
#define NF4 6000   // NT/4

typedef float f4v __attribute__((ext_vector_type(4)));  // native vec for nontemporal builtin

// ---------- kernel 0a: row sums of s ----------
__global__ void k_srow(const float* __restrict__ s, float* __restrict__ srow) {
    int r = blockIdx.x;
    int l = threadIdx.x;
    float v = 0.f;
    for (int j = l; j < NN; j += 64) v += s[r * NN + j];
    #pragma unroll
    for (int o = 32; o; o >>= 1) v += __shfl_xor(v, o);
    if (l == 0) srow[r] = v;
}

// ---------- kernel 0b: rowsum[k] = (47 - k/500)*0.8 + srow[k%500] ----------
__global__ void k_rs(const float* __restrict__ srow, float* __restrict__ rs) {
    int k = blockIdx.x * 256 + threadIdx.x;
    if (k < NT) {
        int i = k / NN;
        int v = k - i * NN;
        rs[k] = (float)(TT - 1 - i) * 0.8f + srow[v];
    }
}

// ---------- kernel 1: per-(b,c) softmax over 24000 folded to per-n sums ----------
// Register-lean variant targeting 64 VGPRs -> 8 waves/SIMD -> 4 blocks/CU:
// the barrier-structured block has dead load-issue windows (reduction/gather/
// teardown); 4 resident blocks instead of 2 doubles the load duty cycle.
// x loads are non-temporal (streamed once) to keep rs hot in L2.
__launch_bounds__(512, 8)
__global__ void k_p1(const float* __restrict__ x, const float* __restrict__ rs,
                     float* __restrict__ xws) {
    __shared__ float p[6144];          // per-float4 contributions (f-indexed)
    __shared__ float redm[8], reds[8];
    int bc = blockIdx.x;
    int tid = threadIdx.x;
    int w = tid >> 6, l = tid & 63;
    int f0 = w * 768 + l;

    const f4v* xp = (const f4v*)x + (size_t)bc * NF4;
    const f4v* rp = (const f4v*)rs;

    float sf[12], ml[12];
    float m = 0.f;                     // relu output >= 0, so 0 is a safe identity

    // i = 0..8: f = f0 + 64i <= 5439 + 512 = 5951 < 6000 -> no clamp, no mask
    #pragma unroll
    for (int i = 0; i < 9; i++) {
        int f = f0 + i * 64;
        f4v xv = __builtin_nontemporal_load(xp + f);
        f4v rv = rp[f];
        float y0 = fmaxf(xv.x * rv.x * 0.125f, 0.f);
        float y1 = fmaxf(xv.y * rv.y * 0.125f, 0.f);
        float y2 = fmaxf(xv.z * rv.z * 0.125f, 0.f);
        float y3 = fmaxf(xv.w * rv.w * 0.125f, 0.f);
        float mm = fmaxf(fmaxf(y0, y1), fmaxf(y2, y3));
        sf[i] = __expf(y0 - mm) + __expf(y1 - mm)
              + __expf(y2 - mm) + __expf(y3 - mm);
        ml[i] = mm;
        m = fmaxf(m, mm);
    }
    // i = 9..11: tail can exceed NF4 -> clamp load, zero sf (duplicate values
    // can only echo a real element, so letting them into the max is harmless).
    #pragma unroll
    for (int i = 9; i < 12; i++) {
        int f = f0 + i * 64;
        int fc = (f < NF4) ? f : (NF4 - 1);
        float msk = (f < NF4) ? 1.f : 0.f;
        f4v xv = __builtin_nontemporal_load(xp + fc);
        f4v rv = rp[fc];
        float y0 = fmaxf(xv.x * rv.x * 0.125f, 0.f);
        float y1 = fmaxf(xv.y * rv.y * 0.125f, 0.f);
        float y2 = fmaxf(xv.z * rv.z * 0.125f, 0.f);
        float y3 = fmaxf(xv.w * rv.w * 0.125f, 0.f);
        float mm = fmaxf(fmaxf(y0, y1), fmaxf(y2, y3));
        float sfi = __expf(y0 - mm) + __expf(y1 - mm)
                  + __expf(y2 - mm) + __expf(y3 - mm);
        sf[i] = sfi * msk;
        ml[i] = mm;
        m = fmaxf(m, mm);
    }

    // block max over 8 waves
    #pragma unroll
    for (int o = 32; o; o >>= 1) m = fmaxf(m, __shfl_xor(m, o));
    if (l == 0) redm[w] = m;
    __syncthreads();
    float M = redm[0];
    #pragma unroll
    for (int i = 1; i < 8; i++) M = fmaxf(M, redm[i]);

    // rescale per-float4 sums -> LDS (conflict-free writes), lane total -> Z
    float tot = 0.f;
    #pragma unroll
    for (int i = 0; i < 12; i++) {
        float cf = sf[i] * __expf(ml[i] - M);
        p[f0 + i * 64] = cf;
        tot += cf;
    }
    #pragma unroll
    for (int o = 32; o; o >>= 1) tot += __shfl_xor(tot, o);
    if (l == 0) reds[w] = tot;
    __syncthreads();
    float Z = 0.f;
    #pragma unroll
    for (int i = 0; i < 8; i++) Z += reds[i];

    // thread n gathers node n's 12 consecutive partials
    if (tid < NN) {
        const float* pp = p + tid * 12;
        float sn = 0.f;
        #pragma unroll
        for (int j = 0; j < 12; j++) sn += pp[j];
        xws[(size_t)bc * NN + tid] = sn / Z;
    }
}

// ---------- kernel 2: gram (X^T X over C=64) fused with row softmax ----------
// (unchanged from round 3 for clean attribution of the p1 change)
__launch_bounds__(512, 4)
__global__ void k_p2(const float* __restrict__ xws, float* __restrict__ out) {
    __shared__ __align__(16) float Xs[32 * NN + 16];
    int b = blockIdx.y;
    int rt8 = blockIdx.x;   // 0..7
    int tid = threadIdx.x;

    int rt = tid >> 6, cx = tid & 63;
    int r0 = rt8 * 64 + rt * 8;
    int cb0 = cx * 4, cb1 = cx * 4 + 256;

    float acc[8][8];
    #pragma unroll
    for (int i = 0; i < 8; i++)
        #pragma unroll
        for (int j = 0; j < 8; j++) acc[i][j] = 0.f;

    for (int cbk = 0; cbk < 2; cbk++) {
        // stage channels [32*cbk, 32*cbk+32) of X_b: 4000 float4
        const float4* src4 = (const float4*)(xws + ((size_t)b * 64 + 32 * cbk) * NN);
        __syncthreads();                 // protect previous Xs use
        #pragma unroll
        for (int i = 0; i < 8; i++) {
            int idx = tid + i * 512;
            if (idx < 4000) ((float4*)Xs)[idx] = src4[idx];
        }
        if (tid < 16) Xs[32 * NN + tid] = 0.f;   // zero the guard pad
        __syncthreads();

        #pragma unroll 4
        for (int c = 0; c < 32; c++) {
            const float* row = Xs + c * NN;
            float4 a0 = *(const float4*)(row + r0);       // broadcast (uniform addr)
            float4 a1 = *(const float4*)(row + r0 + 4);
            float4 b0 = *(const float4*)(row + cb0);      // lanes contiguous 16B
            float4 b1 = *(const float4*)(row + cb1);
            float av[8] = {a0.x, a0.y, a0.z, a0.w, a1.x, a1.y, a1.z, a1.w};
            float bv[8] = {b0.x, b0.y, b0.z, b0.w, b1.x, b1.y, b1.z, b1.w};
            #pragma unroll
            for (int i = 0; i < 8; i++)
                #pragma unroll
                for (int j = 0; j < 8; j++)
                    acc[i][j] = fmaf(av[i], bv[j], acc[i][j]);
        }
    }

    bool c1v = (cx <= 60);          // chunk1 cols 256+4cx valid iff cx<=60
    size_t ob = (size_t)b * (NN * NN);
    #pragma unroll 1
    for (int ri = 0; ri < 8; ri++) {
        int r = r0 + ri;
        if (r >= NN) break;         // wave-uniform
        float u[8];
        #pragma unroll
        for (int j = 0; j < 8; j++) u[j] = fmaxf(acc[ri][j], 0.f) * 0.125f;
        float mx = fmaxf(fmaxf(u[0], u[1]), fmaxf(u[2], u[3]));
        if (c1v) mx = fmaxf(mx, fmaxf(fmaxf(u[4], u[5]), fmaxf(u[6], u[7])));
        #pragma unroll
        for (int o = 32; o; o >>= 1) mx = fmaxf(mx, __shfl_xor(mx, o));

        float e[8];
        float es = 0.f;
        #pragma unroll
        for (int j = 0; j < 4; j++) { e[j] = __expf(u[j] - mx); es += e[j]; }
        if (c1v) {
            #pragma unroll
            for (int j = 4; j < 8; j++) { e[j] = __expf(u[j] - mx); es += e[j]; }
        }
        #pragma unroll
        for (int o = 32; o; o >>= 1) es += __shfl_xor(es, o);
        float inv = 1.f / es;

        float4 w0 = make_float4(e[0] * inv, e[1] * inv, e[2] * inv, e[3] * inv);
        *(float4*)(out + ob + (size_t)r * NN + cb0) = w0;
        if (c1v) {
            float4 w1 = make_float4(e[4] * inv, e[5] * inv, e[6] * inv, e[7] * inv);
            *(float4*)(out + ob + (size_t)r * NN + cb1) = w1;
        }
    }
}

extern "C" void kernel_launch(void* const* d_in, const int* in_sizes, int n_in,
                              void* d_out, int out_size, void* d_ws, size_t ws_size,
                              hipStream_t stream) {
    const float* x = (const float*)d_in[0];   // [64,64,500,48]
    const float* s = (const float*)d_in[1];   // [500,500]
    float* out = (float*)d_out;               // [64,500,500]
    float* wsf = (float*)d_ws;

    float* srow = wsf;             // 500 floats
    float* rs   = wsf + 1024;      // 24000 floats
    float* xws  = wsf + 32768;     // 64*64*500 = 2,048,000 floats (~8.2 MB)

    k_srow<<<NN, 64, 0, stream>>>(s, srow);
    k_rs<<<(NT + 255) / 256, 256, 0, stream>>>(srow, rs);
    k_p1<<<64 * 64, 512, 0, stream>>>(x, rs, xws);
    dim3 g2(8, 64);
    k_p2<<<g2, 512, 0, stream>>>(xws, out);
}

// Round 8
// 166.803 us; speedup vs baseline: 2.2259x; 1.0637x over previous
//
#include <hip/hip_runtime.h>
#include <math.h>

#define NN 500
#define TT 48
#define NT 24000   // NN*TT
#define NF4 6000   // NT/4

// ---------- kernel 0a: row sums of s ----------
__global__ void k_srow(const float* __restrict__ s, float* __restrict__ srow) {
    int r = blockIdx.x;
    int l = threadIdx.x;
    float v = 0.f;
    for (int j = l; j < NN; j += 64) v += s[r * NN + j];
    #pragma unroll
    for (int o = 32; o; o >>= 1) v += __shfl_xor(v, o);
    if (l == 0) srow[r] = v;
}

// ---------- kernel 1: per-(b,c) softmax over 24000 folded to per-n sums ----------
// rs is NOT read from global (that was 402 MB of L2-evicted fabric traffic,
// doubling the kernel's data movement). Instead srow (2 KB) is staged in LDS
// and rs[k] = (47 - k/500)*0.8 + srow[k%500] is reconstructed inline.
// Since 500 % 4 == 0, a float4 at k=4f shares one time-index i and reads
// srow[v..v+3] as a single aligned ds_read_b128 (conflict-free pattern).
__launch_bounds__(512, 4)
__global__ void k_p1(const float* __restrict__ x, const float* __restrict__ srow,
                     float* __restrict__ xws) {
    __shared__ float p[6144];          // per-float4 contributions (f-indexed)
    __shared__ __align__(16) float sr[512];   // srow staged (500 used)
    __shared__ float redm[8], reds[8];
    int bc = blockIdx.x;
    int tid = threadIdx.x;
    int w = tid >> 6, l = tid & 63;
    int f0 = w * 768 + l;

    if (tid < NN) sr[tid] = srow[tid];
    __syncthreads();

    const float4* xp = (const float4*)x + (size_t)bc * NF4;

    float sf[12], ml[12];
    float m = 0.f;                     // relu output >= 0, so 0 is a safe identity

    // i = 0..8: f = f0 + 64i <= 5439 + 512 = 5951 < 6000 -> no clamp, no mask
    #pragma unroll
    for (int i = 0; i < 9; i++) {
        int f = f0 + i * 64;
        int kk = 4 * f;
        int ti = kk / 500;             // magic-mul div
        int v  = kk - ti * 500;        // multiple of 4
        float tt = (float)(TT - 1 - ti) * 0.8f;
        float4 sv = *(const float4*)(sr + v);
        float4 xv = xp[f];
        float y0 = fmaxf(xv.x * (tt + sv.x) * 0.125f, 0.f);
        float y1 = fmaxf(xv.y * (tt + sv.y) * 0.125f, 0.f);
        float y2 = fmaxf(xv.z * (tt + sv.z) * 0.125f, 0.f);
        float y3 = fmaxf(xv.w * (tt + sv.w) * 0.125f, 0.f);
        float mm = fmaxf(fmaxf(y0, y1), fmaxf(y2, y3));
        sf[i] = __expf(y0 - mm) + __expf(y1 - mm)
              + __expf(y2 - mm) + __expf(y3 - mm);
        ml[i] = mm;
        m = fmaxf(m, mm);
    }
    // i = 9..11: tail can exceed NF4 -> clamp load, zero sf (clamped duplicate
    // echoes a real element of this row, so letting it into the max is harmless).
    #pragma unroll
    for (int i = 9; i < 12; i++) {
        int f = f0 + i * 64;
        int fc = (f < NF4) ? f : (NF4 - 1);
        float msk = (f < NF4) ? 1.f : 0.f;
        int kk = 4 * fc;
        int ti = kk / 500;
        int v  = kk - ti * 500;
        float tt = (float)(TT - 1 - ti) * 0.8f;
        float4 sv = *(const float4*)(sr + v);
        float4 xv = xp[fc];
        float y0 = fmaxf(xv.x * (tt + sv.x) * 0.125f, 0.f);
        float y1 = fmaxf(xv.y * (tt + sv.y) * 0.125f, 0.f);
        float y2 = fmaxf(xv.z * (tt + sv.z) * 0.125f, 0.f);
        float y3 = fmaxf(xv.w * (tt + sv.w) * 0.125f, 0.f);
        float mm = fmaxf(fmaxf(y0, y1), fmaxf(y2, y3));
        float sfi = __expf(y0 - mm) + __expf(y1 - mm)
                  + __expf(y2 - mm) + __expf(y3 - mm);
        sf[i] = sfi * msk;
        ml[i] = mm;
        m = fmaxf(m, mm);
    }

    // block max over 8 waves
    #pragma unroll
    for (int o = 32; o; o >>= 1) m = fmaxf(m, __shfl_xor(m, o));
    if (l == 0) redm[w] = m;
    __syncthreads();
    float M = redm[0];
    #pragma unroll
    for (int i = 1; i < 8; i++) M = fmaxf(M, redm[i]);

    // rescale per-float4 sums -> LDS (conflict-free writes), lane total -> Z
    float tot = 0.f;
    #pragma unroll
    for (int i = 0; i < 12; i++) {
        float cf = sf[i] * __expf(ml[i] - M);
        p[f0 + i * 64] = cf;
        tot += cf;
    }
    #pragma unroll
    for (int o = 32; o; o >>= 1) tot += __shfl_xor(tot, o);
    if (l == 0) reds[w] = tot;
    __syncthreads();
    float Z = 0.f;
    #pragma unroll
    for (int i = 0; i < 8; i++) Z += reds[i];

    // thread n gathers node n's 12 consecutive partials
    if (tid < NN) {
        const float* pp = p + tid * 12;
        float sn = 0.f;
        #pragma unroll
        for (int j = 0; j < 12; j++) sn += pp[j];
        xws[(size_t)bc * NN + tid] = sn / Z;
    }
}

// ---------- kernel 2: gram (X^T X over C=64) fused with row softmax ----------
// (unchanged for clean attribution of the p1 change)
__launch_bounds__(512, 4)
__global__ void k_p2(const float* __restrict__ xws, float* __restrict__ out) {
    __shared__ __align__(16) float Xs[32 * NN + 16];
    int b = blockIdx.y;
    int rt8 = blockIdx.x;   // 0..7
    int tid = threadIdx.x;

    int rt = tid >> 6, cx = tid & 63;
    int r0 = rt8 * 64 + rt * 8;
    int cb0 = cx * 4, cb1 = cx * 4 + 256;

    float acc[8][8];
    #pragma unroll
    for (int i = 0; i < 8; i++)
        #pragma unroll
        for (int j = 0; j < 8; j++) acc[i][j] = 0.f;

    for (int cbk = 0; cbk < 2; cbk++) {
        // stage channels [32*cbk, 32*cbk+32) of X_b: 4000 float4
        const float4* src4 = (const float4*)(xws + ((size_t)b * 64 + 32 * cbk) * NN);
        __syncthreads();                 // protect previous Xs use
        #pragma unroll
        for (int i = 0; i < 8; i++) {
            int idx = tid + i * 512;
            if (idx < 4000) ((float4*)Xs)[idx] = src4[idx];
        }
        if (tid < 16) Xs[32 * NN + tid] = 0.f;   // zero the guard pad
        __syncthreads();

        #pragma unroll 4
        for (int c = 0; c < 32; c++) {
            const float* row = Xs + c * NN;
            float4 a0 = *(const float4*)(row + r0);       // broadcast (uniform addr)
            float4 a1 = *(const float4*)(row + r0 + 4);
            float4 b0 = *(const float4*)(row + cb0);      // lanes contiguous 16B
            float4 b1 = *(const float4*)(row + cb1);
            float av[8] = {a0.x, a0.y, a0.z, a0.w, a1.x, a1.y, a1.z, a1.w};
            float bv[8] = {b0.x, b0.y, b0.z, b0.w, b1.x, b1.y, b1.z, b1.w};
            #pragma unroll
            for (int i = 0; i < 8; i++)
                #pragma unroll
                for (int j = 0; j < 8; j++)
                    acc[i][j] = fmaf(av[i], bv[j], acc[i][j]);
        }
    }

    bool c1v = (cx <= 60);          // chunk1 cols 256+4cx valid iff cx<=60
    size_t ob = (size_t)b * (NN * NN);
    #pragma unroll 1
    for (int ri = 0; ri < 8; ri++) {
        int r = r0 + ri;
        if (r >= NN) break;         // wave-uniform
        float u[8];
        #pragma unroll
        for (int j = 0; j < 8; j++) u[j] = fmaxf(acc[ri][j], 0.f) * 0.125f;
        float mx = fmaxf(fmaxf(u[0], u[1]), fmaxf(u[2], u[3]));
        if (c1v) mx = fmaxf(mx, fmaxf(fmaxf(u[4], u[5]), fmaxf(u[6], u[7])));
        #pragma unroll
        for (int o = 32; o; o >>= 1) mx = fmaxf(mx, __shfl_xor(mx, o));

        float e[8];
        float es = 0.f;
        #pragma unroll
        for (int j = 0; j < 4; j++) { e[j] = __expf(u[j] - mx); es += e[j]; }
        if (c1v) {
            #pragma unroll
            for (int j = 4; j < 8; j++) { e[j] = __expf(u[j] - mx); es += e[j]; }
        }
        #pragma unroll
        for (int o = 32; o; o >>= 1) es += __shfl_xor(es, o);
        float inv = 1.f / es;

        float4 w0 = make_float4(e[0] * inv, e[1] * inv, e[2] * inv, e[3] * inv);
        *(float4*)(out + ob + (size_t)r * NN + cb0) = w0;
        if (c1v) {
            float4 w1 = make_float4(e[4] * inv, e[5] * inv, e[6] * inv, e[7] * inv);
            *(float4*)(out + ob + (size_t)r * NN + cb1) = w1;
        }
    }
}

extern "C" void kernel_launch(void* const* d_in, const int* in_sizes, int n_in,
                              void* d_out, int out_size, void* d_ws, size_t ws_size,
                              hipStream_t stream) {
    const float* x = (const float*)d_in[0];   // [64,64,500,48]
    const float* s = (const float*)d_in[1];   // [500,500]
    float* out = (float*)d_out;               // [64,500,500]
    float* wsf = (float*)d_ws;

    float* srow = wsf;             // 500 floats
    float* xws  = wsf + 32768;     // 64*64*500 = 2,048,000 floats (~8.2 MB)

    k_srow<<<NN, 64, 0, stream>>>(s, srow);
    k_p1<<<64 * 64, 512, 0, stream>>>(x, srow, xws);
    dim3 g2(8, 64);
    k_p2<<<g2, 512, 0, stream>>>(xws, out);
}